// Round 1
// baseline (3907.897 us; speedup 1.0000x reference)
//
#include <hip/hip_runtime.h>

#define SLOPE 0.01f

__device__ __forceinline__ float lrelu(float v) { return v >= 0.f ? v : SLOPE * v; }

// ---------------------------------------------------------------------------
// Generic fp32 GEMM: C[M x 128] = act(A[M x K] @ W[K x 128] + bias)
// Tile: BM=128, BN=128, BK=32. 256 threads, 8x8 outputs/thread.
// A staged transposed in LDS so inner loop uses ds_read_b128.
// ---------------------------------------------------------------------------
template <int RELU>
__global__ __launch_bounds__(256, 2) void gemm128(const float* __restrict__ A,
                                                  const float* __restrict__ W,
                                                  const float* __restrict__ bias,
                                                  float* __restrict__ C,
                                                  int M, int K) {
    __shared__ float As[32][132];  // [k][m], stride 132 keeps 16B alignment, conflicts <=2-way
    __shared__ float Ws[32][132];  // [k][n]

    const int tid = threadIdx.x;
    const int m0 = blockIdx.x * 128;
    const int rg = tid >> 4;        // 0..15 row group
    const int cg = tid & 15;        // 0..15 col group

    const int lm = tid >> 3;        // 0..31  (A-load row within pass)
    const int lc = (tid & 7) * 4;   // 0,4,..28 (A-load k within tile)
    const int wr = tid >> 5;        // 0..7   (W-load k row within pass)
    const int wc = (tid & 31) * 4;  // 0,4,..124

    float acc[8][8];
#pragma unroll
    for (int i = 0; i < 8; i++)
#pragma unroll
        for (int j = 0; j < 8; j++) acc[i][j] = 0.f;

    for (int k0 = 0; k0 < K; k0 += 32) {
        // A tile -> LDS (transposed)
#pragma unroll
        for (int p = 0; p < 4; p++) {
            int row = m0 + lm + p * 32;
            int rc = row < M ? row : M - 1;
            const float4 v = *(const float4*)(A + (size_t)rc * K + k0 + lc);
            As[lc + 0][lm + p * 32] = v.x;
            As[lc + 1][lm + p * 32] = v.y;
            As[lc + 2][lm + p * 32] = v.z;
            As[lc + 3][lm + p * 32] = v.w;
        }
        // W tile -> LDS
#pragma unroll
        for (int p = 0; p < 4; p++) {
            *(float4*)&Ws[wr + p * 8][wc] =
                *(const float4*)(W + (size_t)(k0 + wr + p * 8) * 128 + wc);
        }
        __syncthreads();
#pragma unroll
        for (int kk = 0; kk < 32; kk++) {
            float a[8], b[8];
            *(float4*)&a[0] = *(const float4*)&As[kk][rg * 4];
            *(float4*)&a[4] = *(const float4*)&As[kk][64 + rg * 4];
            *(float4*)&b[0] = *(const float4*)&Ws[kk][cg * 4];
            *(float4*)&b[4] = *(const float4*)&Ws[kk][64 + cg * 4];
#pragma unroll
            for (int i = 0; i < 8; i++)
#pragma unroll
                for (int j = 0; j < 8; j++) acc[i][j] = fmaf(a[i], b[j], acc[i][j]);
        }
        __syncthreads();
    }

    // epilogue
    float4 b0 = *(const float4*)(bias + cg * 4);
    float4 b1 = *(const float4*)(bias + 64 + cg * 4);
#pragma unroll
    for (int i = 0; i < 8; i++) {
        int row = m0 + ((i < 4) ? (rg * 4 + i) : (64 + rg * 4 + (i - 4)));
        if (row >= M) continue;
        float4 o0, o1;
        o0.x = acc[i][0] + b0.x; o0.y = acc[i][1] + b0.y;
        o0.z = acc[i][2] + b0.z; o0.w = acc[i][3] + b0.w;
        o1.x = acc[i][4] + b1.x; o1.y = acc[i][5] + b1.y;
        o1.z = acc[i][6] + b1.z; o1.w = acc[i][7] + b1.w;
        if (RELU) {
            o0.x = lrelu(o0.x); o0.y = lrelu(o0.y); o0.z = lrelu(o0.z); o0.w = lrelu(o0.w);
            o1.x = lrelu(o1.x); o1.y = lrelu(o1.y); o1.z = lrelu(o1.z); o1.w = lrelu(o1.w);
        }
        *(float4*)(C + (size_t)row * 128 + cg * 4) = o0;
        *(float4*)(C + (size_t)row * 128 + 64 + cg * 4) = o1;
    }
}

// ---------------------------------------------------------------------------
// Fused RGCN output GEMM:
//   C = x@Wroot + (agg0/max(deg0,1))@W0 + (agg1/max(deg1,1))@W1 + bias
// Same tile structure; loops 3 segments of K=128 with per-row scaling.
// ---------------------------------------------------------------------------
__global__ __launch_bounds__(256, 2) void rgcn_gemm(const float* __restrict__ x,
                                                    const float* __restrict__ agg0,
                                                    const float* __restrict__ agg1,
                                                    const float* __restrict__ deg0,
                                                    const float* __restrict__ deg1,
                                                    const float* __restrict__ Wroot,
                                                    const float* __restrict__ W0,
                                                    const float* __restrict__ W1,
                                                    const float* __restrict__ bias,
                                                    float* __restrict__ C, int M) {
    __shared__ float As[32][132];
    __shared__ float Ws[32][132];

    const int tid = threadIdx.x;
    const int m0 = blockIdx.x * 128;
    const int rg = tid >> 4;
    const int cg = tid & 15;
    const int lm = tid >> 3;
    const int lc = (tid & 7) * 4;
    const int wr = tid >> 5;
    const int wc = (tid & 31) * 4;

    float acc[8][8];
#pragma unroll
    for (int i = 0; i < 8; i++)
#pragma unroll
        for (int j = 0; j < 8; j++) acc[i][j] = 0.f;

    const float* Aseg[3] = {x, agg0, agg1};
    const float* Wseg[3] = {Wroot, W0, W1};
    const float* Dseg[3] = {nullptr, deg0, deg1};

    for (int seg = 0; seg < 3; seg++) {
        const float* Ap = Aseg[seg];
        const float* Wp = Wseg[seg];
        const float* dg = Dseg[seg];
        for (int k0 = 0; k0 < 128; k0 += 32) {
#pragma unroll
            for (int p = 0; p < 4; p++) {
                int row = m0 + lm + p * 32;
                int rc = row < M ? row : M - 1;
                float sc = 1.f;
                if (seg) {
                    float dv = dg[rc];
                    sc = 1.f / (dv > 1.f ? dv : 1.f);
                }
                const float4 v = *(const float4*)(Ap + (size_t)rc * 128 + k0 + lc);
                As[lc + 0][lm + p * 32] = v.x * sc;
                As[lc + 1][lm + p * 32] = v.y * sc;
                As[lc + 2][lm + p * 32] = v.z * sc;
                As[lc + 3][lm + p * 32] = v.w * sc;
            }
#pragma unroll
            for (int p = 0; p < 4; p++) {
                *(float4*)&Ws[wr + p * 8][wc] =
                    *(const float4*)(Wp + (size_t)(k0 + wr + p * 8) * 128 + wc);
            }
            __syncthreads();
#pragma unroll
            for (int kk = 0; kk < 32; kk++) {
                float a[8], b[8];
                *(float4*)&a[0] = *(const float4*)&As[kk][rg * 4];
                *(float4*)&a[4] = *(const float4*)&As[kk][64 + rg * 4];
                *(float4*)&b[0] = *(const float4*)&Ws[kk][cg * 4];
                *(float4*)&b[4] = *(const float4*)&Ws[kk][64 + cg * 4];
#pragma unroll
                for (int i = 0; i < 8; i++)
#pragma unroll
                    for (int j = 0; j < 8; j++) acc[i][j] = fmaf(a[i], b[j], acc[i][j]);
            }
            __syncthreads();
        }
    }

    float4 b0 = *(const float4*)(bias + cg * 4);
    float4 b1 = *(const float4*)(bias + 64 + cg * 4);
#pragma unroll
    for (int i = 0; i < 8; i++) {
        int row = m0 + ((i < 4) ? (rg * 4 + i) : (64 + rg * 4 + (i - 4)));
        if (row >= M) continue;
        float4 o0, o1;
        o0.x = acc[i][0] + b0.x; o0.y = acc[i][1] + b0.y;
        o0.z = acc[i][2] + b0.z; o0.w = acc[i][3] + b0.w;
        o1.x = acc[i][4] + b1.x; o1.y = acc[i][5] + b1.y;
        o1.z = acc[i][6] + b1.z; o1.w = acc[i][7] + b1.w;
        *(float4*)(C + (size_t)row * 128 + cg * 4) = o0;
        *(float4*)(C + (size_t)row * 128 + 64 + cg * 4) = o1;
    }
}

// ---------------------------------------------------------------------------
// Edge aggregation: one wave per edge, float2 per lane.
// agg[r][dst][:] += x[src][:]; deg[r][dst] += 1 (first pass only).
// ---------------------------------------------------------------------------
__global__ __launch_bounds__(256) void edge_agg(const int* __restrict__ ei,
                                                const int* __restrict__ et,
                                                const float* __restrict__ X,
                                                float* __restrict__ agg0,
                                                float* __restrict__ agg1,
                                                float* __restrict__ deg0,
                                                float* __restrict__ deg1,
                                                int E, int computeDeg) {
    const int e = (int)((blockIdx.x * (unsigned)blockDim.x + threadIdx.x) >> 6);
    if (e >= E) return;
    const int lane = threadIdx.x & 63;
    const int s = ei[e];
    const int d = ei[E + e];
    const int r = et[e];
    const float2 v = *(const float2*)(X + (size_t)s * 128 + lane * 2);
    float* agg = (r == 0) ? agg0 : agg1;
    atomicAdd(&agg[(size_t)d * 128 + lane * 2], v.x);
    atomicAdd(&agg[(size_t)d * 128 + lane * 2 + 1], v.y);
    if (computeDeg && lane == 0) {
        float* deg = (r == 0) ? deg0 : deg1;
        atomicAdd(&deg[d], 1.0f);
    }
}

// ---------------------------------------------------------------------------
// Final projection: out[M x 2] = X[M x 128] @ W[128 x 2] + b. One wave/row.
// ---------------------------------------------------------------------------
__global__ __launch_bounds__(256) void out2_kernel(const float* __restrict__ X,
                                                   const float* __restrict__ W,
                                                   const float* __restrict__ b,
                                                   float* __restrict__ out, int M) {
    const int row = (int)((blockIdx.x * (unsigned)blockDim.x + threadIdx.x) >> 6);
    if (row >= M) return;
    const int lane = threadIdx.x & 63;
    const float* xr = X + (size_t)row * 128;
    float x0 = xr[lane], x1 = xr[lane + 64];
    float s0 = x0 * W[lane * 2 + 0] + x1 * W[(lane + 64) * 2 + 0];
    float s1 = x0 * W[lane * 2 + 1] + x1 * W[(lane + 64) * 2 + 1];
#pragma unroll
    for (int off = 32; off; off >>= 1) {
        s0 += __shfl_down(s0, off);
        s1 += __shfl_down(s1, off);
    }
    if (lane == 0) {
        out[(size_t)row * 2 + 0] = s0 + b[0];
        out[(size_t)row * 2 + 1] = s1 + b[1];
    }
}

extern "C" void kernel_launch(void* const* d_in, const int* in_sizes, int n_in,
                              void* d_out, int out_size, void* d_ws, size_t ws_size,
                              hipStream_t stream) {
    const float* des    = (const float*)d_in[0];
    // d_in[1..3]: tweet/num_prop/cat_prop — unused by the reference
    const int*   ei     = (const int*)d_in[4];   // [2,E]
    const int*   et     = (const int*)d_in[5];   // [E]
    const float* W_des  = (const float*)d_in[6];
    const float* b_des  = (const float*)d_in[7];
    const float* W_in   = (const float*)d_in[8];
    const float* b_in   = (const float*)d_in[9];
    const float* W_rel  = (const float*)d_in[10]; // [2,128,128]
    const float* W_root = (const float*)d_in[11];
    const float* b_rgcn = (const float*)d_in[12];
    const float* W_out1 = (const float*)d_in[13];
    const float* b_out1 = (const float*)d_in[14];
    const float* W_out2 = (const float*)d_in[15];
    const float* b_out2 = (const float*)d_in[16];
    float* out = (float*)d_out;

    const int N = in_sizes[0] / 768;   // 100000
    const int E = in_sizes[5];         // 1600000
    const float* W0 = W_rel;
    const float* W1 = W_rel + 128 * 128;

    float* ws   = (float*)d_ws;
    float* xA   = ws;                  // N*128
    float* xB   = xA + (size_t)N * 128;
    float* agg0 = xB + (size_t)N * 128;
    float* agg1 = agg0 + (size_t)N * 128;
    float* deg0 = agg1 + (size_t)N * 128;
    float* deg1 = deg0 + N;

    const int gemmBlocks = (N + 127) / 128;
    const int edgeBlocks = (int)(((size_t)E * 64 + 255) / 256);
    const int rowBlocks  = (int)(((size_t)N * 64 + 255) / 256);

    // zero agg0, agg1, deg0, deg1 (contiguous)
    hipMemsetAsync(agg0, 0, ((size_t)2 * N * 128 + 2 * N) * sizeof(float), stream);

    // 1. xA = lrelu(des @ W_des + b_des)     [N,768]->[N,128]
    gemm128<1><<<gemmBlocks, 256, 0, stream>>>(des, W_des, b_des, xA, N, 768);
    // 2. xB = lrelu(xA @ W_in + b_in)        [N,128]->[N,128]
    gemm128<1><<<gemmBlocks, 256, 0, stream>>>(xA, W_in, b_in, xB, N, 128);
    // 3. edge aggregation on xB (+deg)
    edge_agg<<<edgeBlocks, 256, 0, stream>>>(ei, et, xB, agg0, agg1, deg0, deg1, E, 1);
    // 4. xA = rgcn(xB)
    rgcn_gemm<<<gemmBlocks, 256, 0, stream>>>(xB, agg0, agg1, deg0, deg1,
                                              W_root, W0, W1, b_rgcn, xA, N);
    // 5. re-zero aggs (deg unchanged), aggregate xA
    hipMemsetAsync(agg0, 0, (size_t)2 * N * 128 * sizeof(float), stream);
    edge_agg<<<edgeBlocks, 256, 0, stream>>>(ei, et, xA, agg0, agg1, deg0, deg1, E, 0);
    // 6. xB = rgcn(xA)
    rgcn_gemm<<<gemmBlocks, 256, 0, stream>>>(xA, agg0, agg1, deg0, deg1,
                                              W_root, W0, W1, b_rgcn, xB, N);
    // 7. xA = lrelu(xB @ W_out1 + b_out1)
    gemm128<1><<<gemmBlocks, 256, 0, stream>>>(xB, W_out1, b_out1, xA, N, 128);
    // 8. out = xA @ W_out2 + b_out2          [N,128]->[N,2]
    out2_kernel<<<rowBlocks, 256, 0, stream>>>(xA, W_out2, b_out2, out, N);
}

// Round 2
// 1652.111 us; speedup vs baseline: 2.3654x; 2.3654x over previous
//
#include <hip/hip_runtime.h>

#define SLOPE 0.01f

__device__ __forceinline__ float lrelu(float v) { return v >= 0.f ? v : SLOPE * v; }

// ---------------------------------------------------------------------------
// Generic fp32 GEMM: C[M x 128] = act(A[M x K] @ W[K x 128] + bias)
// Tile: BM=128, BN=128, BK=32. 256 threads, 8x8 outputs/thread.
// ---------------------------------------------------------------------------
template <int RELU>
__global__ __launch_bounds__(256, 2) void gemm128(const float* __restrict__ A,
                                                  const float* __restrict__ W,
                                                  const float* __restrict__ bias,
                                                  float* __restrict__ C,
                                                  int M, int K) {
    __shared__ float As[32][132];
    __shared__ float Ws[32][132];

    const int tid = threadIdx.x;
    const int m0 = blockIdx.x * 128;
    const int rg = tid >> 4;
    const int cg = tid & 15;
    const int lm = tid >> 3;
    const int lc = (tid & 7) * 4;
    const int wr = tid >> 5;
    const int wc = (tid & 31) * 4;

    float acc[8][8];
#pragma unroll
    for (int i = 0; i < 8; i++)
#pragma unroll
        for (int j = 0; j < 8; j++) acc[i][j] = 0.f;

    for (int k0 = 0; k0 < K; k0 += 32) {
#pragma unroll
        for (int p = 0; p < 4; p++) {
            int row = m0 + lm + p * 32;
            int rc = row < M ? row : M - 1;
            const float4 v = *(const float4*)(A + (size_t)rc * K + k0 + lc);
            As[lc + 0][lm + p * 32] = v.x;
            As[lc + 1][lm + p * 32] = v.y;
            As[lc + 2][lm + p * 32] = v.z;
            As[lc + 3][lm + p * 32] = v.w;
        }
#pragma unroll
        for (int p = 0; p < 4; p++) {
            *(float4*)&Ws[wr + p * 8][wc] =
                *(const float4*)(W + (size_t)(k0 + wr + p * 8) * 128 + wc);
        }
        __syncthreads();
#pragma unroll
        for (int kk = 0; kk < 32; kk++) {
            float a[8], b[8];
            *(float4*)&a[0] = *(const float4*)&As[kk][rg * 4];
            *(float4*)&a[4] = *(const float4*)&As[kk][64 + rg * 4];
            *(float4*)&b[0] = *(const float4*)&Ws[kk][cg * 4];
            *(float4*)&b[4] = *(const float4*)&Ws[kk][64 + cg * 4];
#pragma unroll
            for (int i = 0; i < 8; i++)
#pragma unroll
                for (int j = 0; j < 8; j++) acc[i][j] = fmaf(a[i], b[j], acc[i][j]);
        }
        __syncthreads();
    }

    float4 b0 = *(const float4*)(bias + cg * 4);
    float4 b1 = *(const float4*)(bias + 64 + cg * 4);
#pragma unroll
    for (int i = 0; i < 8; i++) {
        int row = m0 + ((i < 4) ? (rg * 4 + i) : (64 + rg * 4 + (i - 4)));
        if (row >= M) continue;
        float4 o0, o1;
        o0.x = acc[i][0] + b0.x; o0.y = acc[i][1] + b0.y;
        o0.z = acc[i][2] + b0.z; o0.w = acc[i][3] + b0.w;
        o1.x = acc[i][4] + b1.x; o1.y = acc[i][5] + b1.y;
        o1.z = acc[i][6] + b1.z; o1.w = acc[i][7] + b1.w;
        if (RELU) {
            o0.x = lrelu(o0.x); o0.y = lrelu(o0.y); o0.z = lrelu(o0.z); o0.w = lrelu(o0.w);
            o1.x = lrelu(o1.x); o1.y = lrelu(o1.y); o1.z = lrelu(o1.z); o1.w = lrelu(o1.w);
        }
        *(float4*)(C + (size_t)row * 128 + cg * 4) = o0;
        *(float4*)(C + (size_t)row * 128 + 64 + cg * 4) = o1;
    }
}

// ---------------------------------------------------------------------------
// Fused RGCN output GEMM: C = x@Wroot + agg0@W0 + agg1@W1 + bias
// (agg rows are already mean-normalized by agg_csr)
// ---------------------------------------------------------------------------
__global__ __launch_bounds__(256, 2) void rgcn_gemm(const float* __restrict__ x,
                                                    const float* __restrict__ agg0,
                                                    const float* __restrict__ agg1,
                                                    const float* __restrict__ Wroot,
                                                    const float* __restrict__ W0,
                                                    const float* __restrict__ W1,
                                                    const float* __restrict__ bias,
                                                    float* __restrict__ C, int M) {
    __shared__ float As[32][132];
    __shared__ float Ws[32][132];

    const int tid = threadIdx.x;
    const int m0 = blockIdx.x * 128;
    const int rg = tid >> 4;
    const int cg = tid & 15;
    const int lm = tid >> 3;
    const int lc = (tid & 7) * 4;
    const int wr = tid >> 5;
    const int wc = (tid & 31) * 4;

    float acc[8][8];
#pragma unroll
    for (int i = 0; i < 8; i++)
#pragma unroll
        for (int j = 0; j < 8; j++) acc[i][j] = 0.f;

    const float* Aseg[3] = {x, agg0, agg1};
    const float* Wseg[3] = {Wroot, W0, W1};

    for (int seg = 0; seg < 3; seg++) {
        const float* Ap = Aseg[seg];
        const float* Wp = Wseg[seg];
        for (int k0 = 0; k0 < 128; k0 += 32) {
#pragma unroll
            for (int p = 0; p < 4; p++) {
                int row = m0 + lm + p * 32;
                int rc = row < M ? row : M - 1;
                const float4 v = *(const float4*)(Ap + (size_t)rc * 128 + k0 + lc);
                As[lc + 0][lm + p * 32] = v.x;
                As[lc + 1][lm + p * 32] = v.y;
                As[lc + 2][lm + p * 32] = v.z;
                As[lc + 3][lm + p * 32] = v.w;
            }
#pragma unroll
            for (int p = 0; p < 4; p++) {
                *(float4*)&Ws[wr + p * 8][wc] =
                    *(const float4*)(Wp + (size_t)(k0 + wr + p * 8) * 128 + wc);
            }
            __syncthreads();
#pragma unroll
            for (int kk = 0; kk < 32; kk++) {
                float a[8], b[8];
                *(float4*)&a[0] = *(const float4*)&As[kk][rg * 4];
                *(float4*)&a[4] = *(const float4*)&As[kk][64 + rg * 4];
                *(float4*)&b[0] = *(const float4*)&Ws[kk][cg * 4];
                *(float4*)&b[4] = *(const float4*)&Ws[kk][64 + cg * 4];
#pragma unroll
                for (int i = 0; i < 8; i++)
#pragma unroll
                    for (int j = 0; j < 8; j++) acc[i][j] = fmaf(a[i], b[j], acc[i][j]);
            }
            __syncthreads();
        }
    }

    float4 b0 = *(const float4*)(bias + cg * 4);
    float4 b1 = *(const float4*)(bias + 64 + cg * 4);
#pragma unroll
    for (int i = 0; i < 8; i++) {
        int row = m0 + ((i < 4) ? (rg * 4 + i) : (64 + rg * 4 + (i - 4)));
        if (row >= M) continue;
        float4 o0, o1;
        o0.x = acc[i][0] + b0.x; o0.y = acc[i][1] + b0.y;
        o0.z = acc[i][2] + b0.z; o0.w = acc[i][3] + b0.w;
        o1.x = acc[i][4] + b1.x; o1.y = acc[i][5] + b1.y;
        o1.z = acc[i][6] + b1.z; o1.w = acc[i][7] + b1.w;
        *(float4*)(C + (size_t)row * 128 + cg * 4) = o0;
        *(float4*)(C + (size_t)row * 128 + 64 + cg * 4) = o1;
    }
}

// ---------------------------------------------------------------------------
// CSR build: histogram -> 3-stage exclusive scan -> scatter
// Bucket id = r*N + dst  (2N buckets total)
// ---------------------------------------------------------------------------
__global__ __launch_bounds__(256) void hist_kernel(const int* __restrict__ ei,
                                                   const int* __restrict__ et,
                                                   int* __restrict__ cnt, int E, int N) {
    int e = blockIdx.x * 256 + threadIdx.x;
    if (e >= E) return;
    int d = ei[E + e];
    int r = et[e];
    atomicAdd(&cnt[r * N + d], 1);
}

// s1: per-chunk (1024 elems) sums
__global__ __launch_bounds__(256) void scan_partial(const int* __restrict__ cnt,
                                                    int* __restrict__ partials, int n) {
    __shared__ int sm[256];
    int base = blockIdx.x * 1024;
    int t = threadIdx.x;
    int s = 0;
#pragma unroll
    for (int i = 0; i < 4; i++) {
        int idx = base + t * 4 + i;
        if (idx < n) s += cnt[idx];
    }
    sm[t] = s;
    __syncthreads();
    for (int off = 128; off; off >>= 1) {
        if (t < off) sm[t] += sm[t + off];
        __syncthreads();
    }
    if (t == 0) partials[blockIdx.x] = sm[0];
}

// s2: single-wave exclusive scan of partials (nb <= a few hundred)
__global__ __launch_bounds__(64) void scan_top(int* __restrict__ partials, int nb,
                                               int* __restrict__ off, int n, int total) {
    int lane = threadIdx.x;
    int base = 0;
    for (int start = 0; start < nb; start += 64) {
        int idx = start + lane;
        int v = (idx < nb) ? partials[idx] : 0;
        int incl = v;
#pragma unroll
        for (int o = 1; o < 64; o <<= 1) {
            int t = __shfl_up(incl, o);
            if (lane >= o) incl += t;
        }
        if (idx < nb) partials[idx] = base + incl - v;  // exclusive
        base += __shfl(incl, 63);
    }
    if (lane == 0) off[n] = total;
}

// s3: one wave per chunk: exclusive scan of the 1024-chunk, add chunk base
__global__ __launch_bounds__(64) void scan_chunk(const int* __restrict__ cnt,
                                                 const int* __restrict__ partials,
                                                 int* __restrict__ off, int n) {
    int lane = threadIdx.x;
    int base = partials[blockIdx.x];
    int cbase = blockIdx.x * 1024;
    for (int i = 0; i < 16; i++) {
        int idx = cbase + i * 64 + lane;
        int v = (idx < n) ? cnt[idx] : 0;
        int incl = v;
#pragma unroll
        for (int o = 1; o < 64; o <<= 1) {
            int t = __shfl_up(incl, o);
            if (lane >= o) incl += t;
        }
        if (idx < n) off[idx] = base + incl - v;
        base += __shfl(incl, 63);
    }
}

__global__ __launch_bounds__(256) void scatter_kernel(const int* __restrict__ ei,
                                                      const int* __restrict__ et,
                                                      const int* __restrict__ off,
                                                      int* __restrict__ cur,
                                                      int* __restrict__ sorted_src,
                                                      int E, int N) {
    int e = blockIdx.x * 256 + threadIdx.x;
    if (e >= E) return;
    int s = ei[e];
    int d = ei[E + e];
    int r = et[e];
    int b = r * N + d;
    int pos = off[b] + atomicAdd(&cur[b], 1);
    sorted_src[pos] = s;
}

// ---------------------------------------------------------------------------
// CSR aggregation: one wave per bucket (r*N+d). lanes hold float2 of D=128.
// Writes mean-normalized agg row (zero if no edges).
// ---------------------------------------------------------------------------
__global__ __launch_bounds__(256) void agg_csr(const int* __restrict__ off,
                                               const int* __restrict__ sorted_src,
                                               const float* __restrict__ X,
                                               float* __restrict__ agg0,
                                               float* __restrict__ agg1,
                                               int N) {
    int w = (int)((blockIdx.x * (unsigned)blockDim.x + threadIdx.x) >> 6);
    if (w >= 2 * N) return;
    int lane = threadIdx.x & 63;
    int start = off[w];
    int end = off[w + 1];
    float2 sum = {0.f, 0.f};
    for (int i = start; i < end; i++) {
        int s = sorted_src[i];
        float2 v = *(const float2*)(X + (size_t)s * 128 + lane * 2);
        sum.x += v.x;
        sum.y += v.y;
    }
    int deg = end - start;
    float inv = (deg > 1) ? (1.f / (float)deg) : 1.f;
    sum.x *= inv;
    sum.y *= inv;
    float* agg = (w < N) ? agg0 : agg1;
    int d = (w < N) ? w : w - N;
    *(float2*)(agg + (size_t)d * 128 + lane * 2) = sum;
}

// ---------------------------------------------------------------------------
// Final projection: out[M x 2] = X[M x 128] @ W[128 x 2] + b. One wave/row.
// ---------------------------------------------------------------------------
__global__ __launch_bounds__(256) void out2_kernel(const float* __restrict__ X,
                                                   const float* __restrict__ W,
                                                   const float* __restrict__ b,
                                                   float* __restrict__ out, int M) {
    const int row = (int)((blockIdx.x * (unsigned)blockDim.x + threadIdx.x) >> 6);
    if (row >= M) return;
    const int lane = threadIdx.x & 63;
    const float* xr = X + (size_t)row * 128;
    float x0 = xr[lane], x1 = xr[lane + 64];
    float s0 = x0 * W[lane * 2 + 0] + x1 * W[(lane + 64) * 2 + 0];
    float s1 = x0 * W[lane * 2 + 1] + x1 * W[(lane + 64) * 2 + 1];
#pragma unroll
    for (int off = 32; off; off >>= 1) {
        s0 += __shfl_down(s0, off);
        s1 += __shfl_down(s1, off);
    }
    if (lane == 0) {
        out[(size_t)row * 2 + 0] = s0 + b[0];
        out[(size_t)row * 2 + 1] = s1 + b[1];
    }
}

extern "C" void kernel_launch(void* const* d_in, const int* in_sizes, int n_in,
                              void* d_out, int out_size, void* d_ws, size_t ws_size,
                              hipStream_t stream) {
    const float* des    = (const float*)d_in[0];
    const int*   ei     = (const int*)d_in[4];
    const int*   et     = (const int*)d_in[5];
    const float* W_des  = (const float*)d_in[6];
    const float* b_des  = (const float*)d_in[7];
    const float* W_in   = (const float*)d_in[8];
    const float* b_in   = (const float*)d_in[9];
    const float* W_rel  = (const float*)d_in[10];
    const float* W_root = (const float*)d_in[11];
    const float* b_rgcn = (const float*)d_in[12];
    const float* W_out1 = (const float*)d_in[13];
    const float* b_out1 = (const float*)d_in[14];
    const float* W_out2 = (const float*)d_in[15];
    const float* b_out2 = (const float*)d_in[16];
    float* out = (float*)d_out;

    const int N = in_sizes[0] / 768;   // 100000
    const int E = in_sizes[5];         // 1600000
    const int TWO_N = 2 * N;
    const float* W0 = W_rel;
    const float* W1 = W_rel + 128 * 128;

    float* ws    = (float*)d_ws;
    float* xA    = ws;                            // N*128 f32
    float* xB    = xA + (size_t)N * 128;          // N*128
    float* agg0  = xB + (size_t)N * 128;          // N*128
    float* agg1  = agg0 + (size_t)N * 128;        // N*128
    int*   cnt   = (int*)(agg1 + (size_t)N * 128);  // 2N
    int*   cur   = cnt + TWO_N;                     // 2N
    int*   off   = cur + TWO_N;                     // 2N+1
    int*   parts = off + TWO_N + 1;                 // ~256
    int*   ssrc  = parts + 256;                     // E

    const int gemmBlocks = (N + 127) / 128;
    const int edgeBlocks = (E + 255) / 256;
    const int aggBlocks  = (TWO_N + 3) / 4;   // 4 waves per 256-thread block
    const int rowBlocks  = (int)(((size_t)N * 64 + 255) / 256);
    const int nChunks    = (TWO_N + 1023) / 1024;

    // ---- build CSR (once, reused by both agg passes) ----
    hipMemsetAsync(cnt, 0, (size_t)2 * TWO_N * sizeof(int), stream);  // cnt + cur
    hist_kernel<<<edgeBlocks, 256, 0, stream>>>(ei, et, cnt, E, N);
    scan_partial<<<nChunks, 256, 0, stream>>>(cnt, parts, TWO_N);
    scan_top<<<1, 64, 0, stream>>>(parts, nChunks, off, TWO_N, E);
    scan_chunk<<<nChunks, 64, 0, stream>>>(cnt, parts, off, TWO_N);
    scatter_kernel<<<edgeBlocks, 256, 0, stream>>>(ei, et, off, cur, ssrc, E, N);

    // ---- pipeline ----
    gemm128<1><<<gemmBlocks, 256, 0, stream>>>(des, W_des, b_des, xA, N, 768);
    gemm128<1><<<gemmBlocks, 256, 0, stream>>>(xA, W_in, b_in, xB, N, 128);

    agg_csr<<<aggBlocks, 256, 0, stream>>>(off, ssrc, xB, agg0, agg1, N);
    rgcn_gemm<<<gemmBlocks, 256, 0, stream>>>(xB, agg0, agg1, W_root, W0, W1, b_rgcn, xA, N);

    agg_csr<<<aggBlocks, 256, 0, stream>>>(off, ssrc, xA, agg0, agg1, N);
    rgcn_gemm<<<gemmBlocks, 256, 0, stream>>>(xA, agg0, agg1, W_root, W0, W1, b_rgcn, xB, N);

    gemm128<1><<<gemmBlocks, 256, 0, stream>>>(xB, W_out1, b_out1, xA, N, 128);
    out2_kernel<<<rowBlocks, 256, 0, stream>>>(xA, W_out2, b_out2, out, N);
}